// Round 4
// baseline (470.451 us; speedup 1.0000x reference)
//
#include <hip/hip_runtime.h>
#include <hip/hip_bf16.h>
#include <math.h>

#define DEV __device__ __forceinline__

constexpr int B  = 8,  N = 16, P = 128, PL = 16;
constexpr int D  = 128, DS = 16, DTR = 8, DFF = 256, EL = 2;
constexpr int L  = N * P + 1;            // 2049
constexpr int BL = B * L;                // 16392
constexpr int CT = 32;                   // scan chunk length
constexpr int NC = (L + CT - 1) / CT;    // 65
constexpr int MT128 = (BL + 127) / 128;  // 129
constexpr int MT64  = (BL + 63) / 64;    // 257
constexpr int KS = 136;                  // LDS row stride (bf16) for 128-wide K chunk

using bf16x8 = __attribute__((ext_vector_type(8))) __bf16;
using f32x4  = __attribute__((ext_vector_type(4))) float;

DEV float sigmoidf_(float x) { return 1.0f / (1.0f + __expf(-x)); }

DEV float wsum(float v) {
#pragma unroll
  for (int m = 32; m; m >>= 1) v += __shfl_xor(v, m, 64);
  return v;
}

// r^(n+1) for n=0..15, depth-4 tree (replaces serial p*=r chain)
DEV void pow_tree(float r, float* pw) {
  float r2 = r * r;
  float r3 = r2 * r;
  float r4 = r2 * r2;
  float r8 = r4 * r4;
  float r12 = r8 * r4;
  pw[0] = r;       pw[1] = r2;      pw[2] = r3;      pw[3] = r4;
  pw[4] = r4 * r;  pw[5] = r4 * r2; pw[6] = r4 * r3; pw[7] = r8;
  pw[8] = r8 * r;  pw[9] = r8 * r2; pw[10] = r8 * r3; pw[11] = r12;
  pw[12] = r12 * r; pw[13] = r12 * r2; pw[14] = r12 * r3; pw[15] = r12 * r4;
}

// A_n check: A_init = log(1..16) broadcast -> A_n = -(n+1) exactly.
DEV bool an_is_linear(const float* An) {
  bool ok = true;
#pragma unroll
  for (int n = 0; n < DS; ++n)
    ok = ok && (fabsf(An[n] + (float)(n + 1)) < 1e-3f * (n + 1));
  return ok;
}

// ---------------- weight prep ----------------
// weff[l][dir][col][256]: col<128 (x): k-chunk0 = in_w*conv_w0, chunk1 = in_w*conv_w1
//                         col>=128 (z): chunk0 = 0, chunk1 = in_w
__global__ __launch_bounds__(256) void k_prep(
    const float* __restrict__ in_w, const float* __restrict__ conv_w,
    const float* __restrict__ xproj, const float* __restrict__ out_w,
    const float* __restrict__ w1, const float* __restrict__ w2,
    __bf16* __restrict__ weff, __bf16* __restrict__ xpw_bf,
    __bf16* __restrict__ outw_bf, __bf16* __restrict__ w1_bf,
    __bf16* __restrict__ w2_bf)
{
  int g = blockIdx.x * 256 + threadIdx.x;
  if (g < 262144) {
    int l = g >> 17;
    int r = g & 131071;
    int dir = r >> 16;
    int r2 = r & 65535;
    int col = r2 >> 8;
    int kk = r2 & 255;
    int chunk = kk >> 7, k = kk & 127;
    int ld = l * 2 + dir;
    float v;
    if (col < 128) {
      v = in_w[((size_t)ld * 256 + col) * 128 + k] *
          conv_w[((size_t)ld * 128 + col) * 2 + chunk];
    } else {
      v = chunk ? in_w[((size_t)ld * 256 + col) * 128 + k] : 0.f;
    }
    weff[((size_t)ld * 256 + col) * 256 + chunk * 128 + k] = (__bf16)v;
    return;
  }
  g -= 262144;
  if (g < 20480) { xpw_bf[g] = (__bf16)xproj[g]; return; }
  g -= 20480;
  if (g < 65536) {
    int k = g & 127; int q = g >> 7; int n = q & 127; int q2 = q >> 7;
    int dir = q2 & 1; int l = q2 >> 1;
    outw_bf[((size_t)(l * 128 + n)) * 256 + dir * 128 + k] = (__bf16)out_w[g];
    return;
  }
  g -= 65536;
  if (g < 65536) { w1_bf[g] = (__bf16)w1[g]; return; }
  g -= 65536;
  if (g < 65536) { w2_bf[g] = (__bf16)w2[g]; return; }
}

// ---------------- patch embed + view concat -> U (fp32) + Ubf (bf16) ----------------
__global__ __launch_bounds__(256) void k_embed(
    const float* __restrict__ x, const float* __restrict__ view,
    const float* __restrict__ wp_w, const float* __restrict__ wp_b,
    float* __restrict__ U, __bf16* __restrict__ Ubf)
{
  int g = blockIdx.x * 256 + threadIdx.x;
  if (g >= BL * D) return;
  int d = g & (D - 1);
  int row = g >> 7;
  int b = row / L, t = row % L;
  float acc;
  if (t < N * P) {
    const float* xr = x + ((size_t)b * N * P + t) * PL;
    acc = wp_b[d];
#pragma unroll
    for (int k = 0; k < PL; ++k) acc += xr[k] * wp_w[d * PL + k];
  } else {
    acc = view[b * D + d];
  }
  U[(size_t)row * D + d] = acc;
  Ubf[(size_t)row * D + d] = (__bf16)acc;
}

// ---------------- fused xz GEMM + conv + silu ----------------
// grid (2*MT128, 4): y<2 -> x-cols (K=256 over [U[s-1],U[s]]), y>=2 -> z-cols (K=128)
__global__ __launch_bounds__(256) void k_xzc(
    const __bf16* __restrict__ Ubf, const __bf16* __restrict__ Weff,
    const float* __restrict__ conv_b_l,
    float* __restrict__ XCC, __bf16* __restrict__ XCCbf,
    float* __restrict__ Zb)
{
  __shared__ short As[128 * KS];
  __shared__ short Bs[64 * KS];
  int bx = blockIdx.x;
  int rdir = bx / MT128;
  int tile = bx % MT128;
  int col0 = blockIdx.y * 64;
  bool isx = col0 < 128;
  int tid = threadIdx.x;
  int m0 = tile * 128;
  const __bf16* Wb = Weff + (size_t)rdir * 256 * 256;
  int wave = tid >> 6, lane = tid & 63, lm = lane & 15, lq = lane >> 4;
  f32x4 zero4 = {0.f, 0.f, 0.f, 0.f};
  f32x4 acc[2][4];
#pragma unroll
  for (int r = 0; r < 2; ++r)
#pragma unroll
    for (int c = 0; c < 4; ++c) acc[r][c] = zero4;
  int kc0 = isx ? 0 : 1;
  for (int kc = kc0; kc < 2; ++kc) {
    if (kc != kc0) __syncthreads();
    for (int q = tid; q < 128 * 16; q += 256) {
      int rr = q >> 4, g = q & 15;
      int m = m0 + rr;
      int4 v = make_int4(0, 0, 0, 0);
      if (m < BL) {
        int b = m / L, s = m - b * L;
        bool ok = true;
        int idx;
        if (kc == 0) { ok = (s >= 1); idx = rdir ? (L - s) : (s - 1); }
        else         { idx = rdir ? (L - 1 - s) : s; }
        if (ok) v = *(const int4*)(Ubf + ((size_t)b * L + idx) * 128 + g * 8);
      }
      *(int4*)&As[rr * KS + g * 8] = v;
    }
    for (int q = tid; q < 64 * 16; q += 256) {
      int rr = q >> 4, g = q & 15;
      int4 v = *(const int4*)(Wb + (size_t)(col0 + rr) * 256 + kc * 128 + g * 8);
      *(int4*)&Bs[rr * KS + g * 8] = v;
    }
    __syncthreads();
    for (int ks = 0; ks < 128; ks += 32) {
      bf16x8 af[2];
#pragma unroll
      for (int r = 0; r < 2; ++r)
        af[r] = *(const bf16x8*)&As[(wave * 32 + r * 16 + lm) * KS + ks + lq * 8];
#pragma unroll
      for (int c = 0; c < 4; ++c) {
        bf16x8 bfr = *(const bf16x8*)&Bs[(c * 16 + lm) * KS + ks + lq * 8];
#pragma unroll
        for (int r = 0; r < 2; ++r)
          acc[r][c] = __builtin_amdgcn_mfma_f32_16x16x32_bf16(af[r], bfr, acc[r][c], 0, 0, 0);
      }
    }
  }
#pragma unroll
  for (int r = 0; r < 2; ++r) {
    int rowb = m0 + wave * 32 + r * 16 + lq * 4;
#pragma unroll
    for (int c = 0; c < 4; ++c) {
      int col = col0 + c * 16 + lm;
      float cb = isx ? conv_b_l[rdir * 128 + col] : 0.f;
#pragma unroll
      for (int e = 0; e < 4; ++e) {
        int m = rowb + e;
        if (m >= BL) continue;
        size_t base = ((size_t)rdir * BL + m) * 128;
        float v = acc[r][c][e];
        if (isx) {
          v += cb;
          float o = v * sigmoidf_(v);
          XCC[base + col] = o;
          XCCbf[base + col] = (__bf16)o;
        } else {
          Zb[base + col - 128] = v;
        }
      }
    }
  }
}

// ---------------- fused xproj GEMM + dt ----------------
// grid 2*MT128: dbc = xcc @ xproj.T -> BCb; dt = softplus(dbc8 @ dt_w.T + b) -> DT
__global__ __launch_bounds__(256) void k_xproj_dt(
    const __bf16* __restrict__ XCCbf, const __bf16* __restrict__ Wbf,
    const float* __restrict__ dt_w_l, const float* __restrict__ dt_b_l,
    float* __restrict__ BCb, float* __restrict__ DT)
{
  __shared__ short As[128 * KS];
  __shared__ short Bs[64 * KS];
  __shared__ float dbs[128][9];
  int bx = blockIdx.x;
  int rdir = bx / MT128;
  int tile = bx % MT128;
  int tid = threadIdx.x;
  int m0 = tile * 128;
  const __bf16* Wb = Wbf + (size_t)rdir * 40 * 128;
  for (int q = tid; q < 128 * 16; q += 256) {
    int rr = q >> 4, g = q & 15;
    int m = m0 + rr;
    int4 v = make_int4(0, 0, 0, 0);
    if (m < BL) v = *(const int4*)(XCCbf + ((size_t)rdir * BL + m) * 128 + g * 8);
    *(int4*)&As[rr * KS + g * 8] = v;
  }
  for (int q = tid; q < 64 * 16; q += 256) {
    int rr = q >> 4, g = q & 15;
    int4 v = make_int4(0, 0, 0, 0);
    if (rr < 40) v = *(const int4*)(Wb + (size_t)rr * 128 + g * 8);
    *(int4*)&Bs[rr * KS + g * 8] = v;
  }
  __syncthreads();
  int wave = tid >> 6, lane = tid & 63, lm = lane & 15, lq = lane >> 4;
  f32x4 zero4 = {0.f, 0.f, 0.f, 0.f};
  f32x4 acc[2][3];
#pragma unroll
  for (int r = 0; r < 2; ++r)
#pragma unroll
    for (int c = 0; c < 3; ++c) acc[r][c] = zero4;
  for (int ks = 0; ks < 128; ks += 32) {
    bf16x8 af[2];
#pragma unroll
    for (int r = 0; r < 2; ++r)
      af[r] = *(const bf16x8*)&As[(wave * 32 + r * 16 + lm) * KS + ks + lq * 8];
#pragma unroll
    for (int c = 0; c < 3; ++c) {
      bf16x8 bfr = *(const bf16x8*)&Bs[(c * 16 + lm) * KS + ks + lq * 8];
#pragma unroll
      for (int r = 0; r < 2; ++r)
        acc[r][c] = __builtin_amdgcn_mfma_f32_16x16x32_bf16(af[r], bfr, acc[r][c], 0, 0, 0);
    }
  }
#pragma unroll
  for (int r = 0; r < 2; ++r) {
    int rl = wave * 32 + r * 16 + lq * 4;
    int rowb = m0 + rl;
#pragma unroll
    for (int c = 0; c < 3; ++c) {
      int col = c * 16 + lm;
#pragma unroll
      for (int e = 0; e < 4; ++e) {
        int m = rowb + e;
        float v = acc[r][c][e];
        if (col < DTR) dbs[rl + e][col] = v;
        else if (col < DTR + 2 * DS && m < BL)
          BCb[((size_t)rdir * BL + m) * 32 + (col - DTR)] = v;
      }
    }
  }
  __syncthreads();
  // dt: each thread has fixed d = tid&127, rows (tid>>7), step 2
  {
    int dloc = tid & 127;
    int rpar = tid >> 7;
    const float* dw = dt_w_l + ((size_t)rdir * 128 + dloc) * 8;
    float dwr[8];
#pragma unroll
    for (int j = 0; j < 8; ++j) dwr[j] = dw[j];
    float db = dt_b_l[rdir * 128 + dloc];
    for (int rr = rpar; rr < 128; rr += 2) {
      int m = m0 + rr;
      if (m >= BL) break;
      float a = db;
#pragma unroll
      for (int j = 0; j < 8; ++j) a = fmaf(dbs[rr][j], dwr[j], a);
      float dtv = (a > 20.f) ? a : log1pf(__expf(a));
      DT[((size_t)rdir * BL + m) * 128 + dloc] = dtv;
    }
  }
}

// ---------------- scan phase A ----------------
__global__ __launch_bounds__(128) void k_scanA(
    const float* __restrict__ DT, const float* __restrict__ XCC,
    const float* __restrict__ BCb, const float* __restrict__ Alog_l,
    float* __restrict__ HC, float* __restrict__ DTS)
{
  __shared__ float Bs[CT][DS];
  int blk = blockIdx.x;
  int c  = blk % NC;
  int rb = blk / NC;
  int rdir = rb / B;
  int d = threadIdx.x;
  int s0 = c * CT;
  int cnt = min(CT, L - s0);
  size_t rowbase = (size_t)rb * L + s0;
  for (int q = d; q < cnt * DS; q += 128)
    Bs[q >> 4][q & 15] = BCb[(rowbase + (q >> 4)) * 32 + (q & 15)];
  float An[DS];
  const float* Ab = Alog_l + (size_t)rdir * D * DS + (size_t)d * DS;
#pragma unroll
  for (int n = 0; n < DS; ++n) An[n] = -__expf(Ab[n]);
  bool fast = an_is_linear(An);
  __syncthreads();
  float h[DS];
#pragma unroll
  for (int n = 0; n < DS; ++n) h[n] = 0.f;
  float dts = 0.f;
  float dt_nx = DT[rowbase * D + d];
  float xc_nx = XCC[rowbase * D + d];
  if (fast) {
    for (int ss = 0; ss < cnt; ++ss) {
      float dt = dt_nx, xc = xc_nx;
      if (ss + 1 < cnt) {
        size_t ro = (rowbase + ss + 1) * D + d;
        dt_nx = DT[ro]; xc_nx = XCC[ro];
      }
      dts += dt;
      float e = dt * xc;
      float pw[DS];
      pow_tree(__expf(-dt), pw);
#pragma unroll
      for (int n = 0; n < DS; ++n)
        h[n] = fmaf(pw[n], h[n], e * Bs[ss][n]);
    }
  } else {
    for (int ss = 0; ss < cnt; ++ss) {
      float dt = dt_nx, xc = xc_nx;
      if (ss + 1 < cnt) {
        size_t ro = (rowbase + ss + 1) * D + d;
        dt_nx = DT[ro]; xc_nx = XCC[ro];
      }
      dts += dt;
      float e = dt * xc;
#pragma unroll
      for (int n = 0; n < DS; ++n)
        h[n] = __expf(dt * An[n]) * h[n] + e * Bs[ss][n];
    }
  }
  float* hp = HC + ((size_t)blk * D + d) * DS;
#pragma unroll
  for (int n = 0; n < DS; ++n) hp[n] = h[n];
  DTS[(size_t)blk * D + d] = dts;
}

// ---------------- scan phase B ----------------
__global__ __launch_bounds__(128) void k_scanB(
    const float* __restrict__ HC, const float* __restrict__ DTS,
    const float* __restrict__ Alog_l, float* __restrict__ HIN)
{
  int rb = blockIdx.x;
  int rdir = rb / B;
  int d = threadIdx.x;
  float An[DS];
  const float* Ab = Alog_l + (size_t)rdir * D * DS + (size_t)d * DS;
#pragma unroll
  for (int n = 0; n < DS; ++n) An[n] = -__expf(Ab[n]);
  bool fast = an_is_linear(An);
  float h[DS];
#pragma unroll
  for (int n = 0; n < DS; ++n) h[n] = 0.f;
  size_t i0 = ((size_t)(rb * NC) * D + d) * DS;
  float dts_nx = DTS[(size_t)(rb * NC) * D + d];
  float4 h0 = *(const float4*)(HC + i0);
  float4 h1 = *(const float4*)(HC + i0 + 4);
  float4 h2 = *(const float4*)(HC + i0 + 8);
  float4 h3 = *(const float4*)(HC + i0 + 12);
  for (int c = 0; c < NC; ++c) {
    size_t idx = ((size_t)(rb * NC + c) * D + d) * DS;
    float* hin = HIN + idx;
    float hc[DS];
    hc[0]=h0.x; hc[1]=h0.y; hc[2]=h0.z; hc[3]=h0.w;
    hc[4]=h1.x; hc[5]=h1.y; hc[6]=h1.z; hc[7]=h1.w;
    hc[8]=h2.x; hc[9]=h2.y; hc[10]=h2.z; hc[11]=h2.w;
    hc[12]=h3.x; hc[13]=h3.y; hc[14]=h3.z; hc[15]=h3.w;
    float dts = dts_nx;
    if (c + 1 < NC) {
      size_t in2 = ((size_t)(rb * NC + c + 1) * D + d) * DS;
      dts_nx = DTS[(size_t)(rb * NC + c + 1) * D + d];
      h0 = *(const float4*)(HC + in2);
      h1 = *(const float4*)(HC + in2 + 4);
      h2 = *(const float4*)(HC + in2 + 8);
      h3 = *(const float4*)(HC + in2 + 12);
    }
#pragma unroll
    for (int n = 0; n < DS; ++n) hin[n] = h[n];
    if (fast) {
      float pw[DS];
      pow_tree(__expf(-dts), pw);
#pragma unroll
      for (int n = 0; n < DS; ++n)
        h[n] = fmaf(pw[n], h[n], hc[n]);
    } else {
#pragma unroll
      for (int n = 0; n < DS; ++n)
        h[n] = __expf(dts * An[n]) * h[n] + hc[n];
    }
  }
}

// ---------------- scan phase C: emit y bf16 into YMbf (m,[dir*128+d]) ----------------
__global__ __launch_bounds__(128) void k_scanC(
    const float* __restrict__ DT, const float* __restrict__ XCC,
    const float* __restrict__ BCb, const float* __restrict__ Zb,
    const float* __restrict__ HIN, const float* __restrict__ Alog_l,
    const float* __restrict__ Dp_l, __bf16* __restrict__ YMbf)
{
  __shared__ float Bs[CT][DS];
  __shared__ float Cs[CT][DS];
  int blk = blockIdx.x;
  int c  = blk % NC;
  int rb = blk / NC;
  int rdir = rb / B;
  int b = rb % B;
  int d = threadIdx.x;
  int s0 = c * CT;
  int cnt = min(CT, L - s0);
  size_t rowbase = (size_t)rb * L + s0;
  for (int q = d; q < cnt * 2 * DS; q += 128) {
    int ss = q >> 5, j = q & 31;
    float vv = BCb[(rowbase + ss) * 32 + j];
    if (j < DS) Bs[ss][j] = vv; else Cs[ss][j - DS] = vv;
  }
  float An[DS];
  const float* Ab = Alog_l + (size_t)rdir * D * DS + (size_t)d * DS;
#pragma unroll
  for (int n = 0; n < DS; ++n) An[n] = -__expf(Ab[n]);
  bool fast = an_is_linear(An);
  float h[DS];
  const float* hin = HIN + ((size_t)blk * D + d) * DS;
#pragma unroll
  for (int n = 0; n < DS; ++n) h[n] = hin[n];
  float Dpv = Dp_l[rdir * D + d];
  __syncthreads();
  float dt_nx = DT[rowbase * D + d];
  float xc_nx = XCC[rowbase * D + d];
  float z_nx  = Zb[rowbase * D + d];
  if (fast) {
    for (int ss = 0; ss < cnt; ++ss) {
      float dt = dt_nx, xc = xc_nx, z = z_nx;
      if (ss + 1 < cnt) {
        size_t ro = (rowbase + ss + 1) * D + d;
        dt_nx = DT[ro]; xc_nx = XCC[ro]; z_nx = Zb[ro];
      }
      float e = dt * xc;
      float pw[DS];
      pow_tree(__expf(-dt), pw);
      float y = 0.f;
#pragma unroll
      for (int n = 0; n < DS; ++n) {
        h[n] = fmaf(pw[n], h[n], e * Bs[ss][n]);
        y += h[n] * Cs[ss][n];
      }
      y += xc * Dpv;
      y *= z * sigmoidf_(z);
      int s = s0 + ss;
      int tt = rdir ? (L - 1 - s) : s;
      YMbf[((size_t)b * L + tt) * 256 + rdir * 128 + d] = (__bf16)y;
    }
  } else {
    for (int ss = 0; ss < cnt; ++ss) {
      float dt = dt_nx, xc = xc_nx, z = z_nx;
      if (ss + 1 < cnt) {
        size_t ro = (rowbase + ss + 1) * D + d;
        dt_nx = DT[ro]; xc_nx = XCC[ro]; z_nx = Zb[ro];
      }
      float e = dt * xc;
      float y = 0.f;
#pragma unroll
      for (int n = 0; n < DS; ++n) {
        h[n] = __expf(dt * An[n]) * h[n] + e * Bs[ss][n];
        y += h[n] * Cs[ss][n];
      }
      y += xc * Dpv;
      y *= z * sigmoidf_(z);
      int s = s0 + ss;
      int tt = rdir ? (L - 1 - s) : s;
      YMbf[((size_t)b * L + tt) * 256 + rdir * 128 + d] = (__bf16)y;
    }
  }
}

// ---------------- fused out-proj (K=256 both dirs) + residual + LN1 -> XR ----------------
// U never rewritten: post-mamba residual consumed inline by LN.
__global__ __launch_bounds__(256) void k_outln(
    const __bf16* __restrict__ YMbf, const __bf16* __restrict__ Wbf,
    const float* __restrict__ U, const float* __restrict__ g1,
    const float* __restrict__ be1, float* __restrict__ XR,
    __bf16* __restrict__ XRbf)
{
  __shared__ short As[64 * KS];
  __shared__ short Bs[128 * KS];
  int m0 = blockIdx.x * 64;
  int tid = threadIdx.x;
  int wave = tid >> 6, lane = tid & 63, lm = lane & 15, lq = lane >> 4;
  f32x4 zero4 = {0.f, 0.f, 0.f, 0.f};
  f32x4 acc[8];
#pragma unroll
  for (int c = 0; c < 8; ++c) acc[c] = zero4;
  for (int kc = 0; kc < 2; ++kc) {
    if (kc) __syncthreads();
    for (int q = tid; q < 64 * 16; q += 256) {
      int rr = q >> 4, g = q & 15;
      int m = m0 + rr;
      int4 v = make_int4(0, 0, 0, 0);
      if (m < BL) v = *(const int4*)(YMbf + (size_t)m * 256 + kc * 128 + g * 8);
      *(int4*)&As[rr * KS + g * 8] = v;
    }
    for (int q = tid; q < 128 * 16; q += 256) {
      int rr = q >> 4, g = q & 15;
      int4 v = *(const int4*)(Wbf + (size_t)rr * 256 + kc * 128 + g * 8);
      *(int4*)&Bs[rr * KS + g * 8] = v;
    }
    __syncthreads();
    for (int ks = 0; ks < 128; ks += 32) {
      bf16x8 af = *(const bf16x8*)&As[(wave * 16 + lm) * KS + ks + lq * 8];
#pragma unroll
      for (int c = 0; c < 8; ++c) {
        bf16x8 bfr = *(const bf16x8*)&Bs[(c * 16 + lm) * KS + ks + lq * 8];
        acc[c] = __builtin_amdgcn_mfma_f32_16x16x32_bf16(af, bfr, acc[c], 0, 0, 0);
      }
    }
  }
  float g1c[8], be1c[8];
#pragma unroll
  for (int c = 0; c < 8; ++c) {
    int col = c * 16 + lm;
    g1c[c] = g1[col]; be1c[c] = be1[col];
  }
#pragma unroll
  for (int r = 0; r < 4; ++r) {
    int row = m0 + wave * 16 + lq * 4 + r;
    bool valid = row < BL;
    float os[8];
    float sum = 0.f;
#pragma unroll
    for (int c = 0; c < 8; ++c) {
      int col = c * 16 + lm;
      float uv = valid ? U[(size_t)row * 128 + col] : 0.f;
      os[c] = acc[c][r] + uv;
      sum += os[c];
    }
#pragma unroll
    for (int mm = 1; mm < 16; mm <<= 1) sum += __shfl_xor(sum, mm, 64);
    float mean = sum * (1.f / 128.f);
    float qv = 0.f;
#pragma unroll
    for (int c = 0; c < 8; ++c) { float dv = os[c] - mean; qv += dv * dv; }
#pragma unroll
    for (int mm = 1; mm < 16; mm <<= 1) qv += __shfl_xor(qv, mm, 64);
    float inv = rsqrtf(qv * (1.f / 128.f) + 1e-5f);
    if (valid) {
#pragma unroll
      for (int c = 0; c < 8; ++c) {
        int col = c * 16 + lm;
        float o = (os[c] - mean) * inv * g1c[c] + be1c[c];
        XR[(size_t)row * 128 + col] = o;
        XRbf[(size_t)row * 128 + col] = (__bf16)o;
      }
    }
  }
}

// ---------------- FFN1: H = relu(XR @ w1.T + b1) -> bf16 ----------------
__global__ __launch_bounds__(256) void k_ffn1_mfma(
    const __bf16* __restrict__ XRbf, const __bf16* __restrict__ w1bf,
    const float* __restrict__ b1, __bf16* __restrict__ Hbf)
{
  __shared__ short As[128 * KS];
  __shared__ short Bs[64 * KS];
  int m0 = blockIdx.x * 128;
  int col0 = blockIdx.y * 64;
  int tid = threadIdx.x;
  for (int q = tid; q < 128 * 16; q += 256) {
    int rr = q >> 4, g = q & 15;
    int m = m0 + rr;
    int4 v = make_int4(0, 0, 0, 0);
    if (m < BL) v = *(const int4*)(XRbf + (size_t)m * 128 + g * 8);
    *(int4*)&As[rr * KS + g * 8] = v;
  }
  for (int q = tid; q < 64 * 16; q += 256) {
    int rr = q >> 4, g = q & 15;
    int4 v = *(const int4*)(w1bf + (size_t)(col0 + rr) * 128 + g * 8);
    *(int4*)&Bs[rr * KS + g * 8] = v;
  }
  __syncthreads();
  int wave = tid >> 6, lane = tid & 63, lm = lane & 15, lq = lane >> 4;
  f32x4 zero4 = {0.f, 0.f, 0.f, 0.f};
  f32x4 acc[2][4];
#pragma unroll
  for (int r = 0; r < 2; ++r)
#pragma unroll
    for (int c = 0; c < 4; ++c) acc[r][c] = zero4;
  for (int ks = 0; ks < 128; ks += 32) {
    bf16x8 af[2];
#pragma unroll
    for (int r = 0; r < 2; ++r)
      af[r] = *(const bf16x8*)&As[(wave * 32 + r * 16 + lm) * KS + ks + lq * 8];
#pragma unroll
    for (int c = 0; c < 4; ++c) {
      bf16x8 bfr = *(const bf16x8*)&Bs[(c * 16 + lm) * KS + ks + lq * 8];
#pragma unroll
      for (int r = 0; r < 2; ++r)
        acc[r][c] = __builtin_amdgcn_mfma_f32_16x16x32_bf16(af[r], bfr, acc[r][c], 0, 0, 0);
    }
  }
#pragma unroll
  for (int r = 0; r < 2; ++r) {
    int rowb = m0 + wave * 32 + r * 16 + lq * 4;
#pragma unroll
    for (int c = 0; c < 4; ++c) {
      int col = col0 + c * 16 + lm;
      float bb = b1[col];
#pragma unroll
      for (int e = 0; e < 4; ++e) {
        int m = rowb + e;
        if (m < BL)
          Hbf[(size_t)m * 256 + col] = (__bf16)fmaxf(acc[r][c][e] + bb, 0.f);
      }
    }
  }
}

// ---------------- FFN2: (H @ w2.T + b2 + XR) -> LN2 -> U fp32 + Ubf ----------------
__global__ __launch_bounds__(256) void k_ffn2_mfma(
    const __bf16* __restrict__ Hbf, const __bf16* __restrict__ w2bf,
    const float* __restrict__ b2, const float* __restrict__ XR,
    const float* __restrict__ g2, const float* __restrict__ be2,
    float* __restrict__ U, __bf16* __restrict__ Ubf)
{
  __shared__ short As[64 * KS];
  __shared__ short Bs[128 * KS];
  int m0 = blockIdx.x * 64;
  int tid = threadIdx.x;
  int wave = tid >> 6, lane = tid & 63, lm = lane & 15, lq = lane >> 4;
  f32x4 zero4 = {0.f, 0.f, 0.f, 0.f};
  f32x4 acc[8];
#pragma unroll
  for (int c = 0; c < 8; ++c) acc[c] = zero4;
  for (int kc = 0; kc < 2; ++kc) {
    if (kc) __syncthreads();
    for (int q = tid; q < 64 * 16; q += 256) {
      int rr = q >> 4, g = q & 15;
      int m = m0 + rr;
      int4 v = make_int4(0, 0, 0, 0);
      if (m < BL) v = *(const int4*)(Hbf + (size_t)m * 256 + kc * 128 + g * 8);
      *(int4*)&As[rr * KS + g * 8] = v;
    }
    for (int q = tid; q < 128 * 16; q += 256) {
      int rr = q >> 4, g = q & 15;
      int4 v = *(const int4*)(w2bf + (size_t)rr * 256 + kc * 128 + g * 8);
      *(int4*)&Bs[rr * KS + g * 8] = v;
    }
    __syncthreads();
    for (int ks = 0; ks < 128; ks += 32) {
      bf16x8 af = *(const bf16x8*)&As[(wave * 16 + lm) * KS + ks + lq * 8];
#pragma unroll
      for (int c = 0; c < 8; ++c) {
        bf16x8 bfr = *(const bf16x8*)&Bs[(c * 16 + lm) * KS + ks + lq * 8];
        acc[c] = __builtin_amdgcn_mfma_f32_16x16x32_bf16(af, bfr, acc[c], 0, 0, 0);
      }
    }
  }
  float b2c[8], g2c[8], be2c[8];
#pragma unroll
  for (int c = 0; c < 8; ++c) {
    int col = c * 16 + lm;
    b2c[c] = b2[col]; g2c[c] = g2[col]; be2c[c] = be2[col];
  }
#pragma unroll
  for (int r = 0; r < 4; ++r) {
    int row = m0 + wave * 16 + lq * 4 + r;
    bool valid = row < BL;
    float os[8];
    float sum = 0.f;
#pragma unroll
    for (int c = 0; c < 8; ++c) {
      int col = c * 16 + lm;
      float xr = valid ? XR[(size_t)row * 128 + col] : 0.f;
      os[c] = acc[c][r] + b2c[c] + xr;
      sum += os[c];
    }
#pragma unroll
    for (int mm = 1; mm < 16; mm <<= 1) sum += __shfl_xor(sum, mm, 64);
    float mean = sum * (1.f / 128.f);
    float qv = 0.f;
#pragma unroll
    for (int c = 0; c < 8; ++c) { float dv = os[c] - mean; qv += dv * dv; }
#pragma unroll
    for (int mm = 1; mm < 16; mm <<= 1) qv += __shfl_xor(qv, mm, 64);
    float inv = rsqrtf(qv * (1.f / 128.f) + 1e-5f);
    if (valid) {
#pragma unroll
      for (int c = 0; c < 8; ++c) {
        int col = c * 16 + lm;
        float o = (os[c] - mean) * inv * g2c[c] + be2c[c];
        U[(size_t)row * 128 + col] = o;
        Ubf[(size_t)row * 128 + col] = (__bf16)o;
      }
    }
  }
}

// ---------------- final LN + slice + transpose -> out (B,N,D,P) ----------------
__global__ __launch_bounds__(256) void k_lnf_out(
    const float* __restrict__ U, const float* __restrict__ g,
    const float* __restrict__ be, float* __restrict__ out)
{
  int gg = blockIdx.x * 4 + (threadIdx.x >> 6);   // [0, B*2048)
  int lane = threadIdx.x & 63;
  int b = gg >> 11, t = gg & 2047;
  const float* ur = U + ((size_t)b * L + t) * D;
  float x0 = ur[lane], x1 = ur[lane + 64];
  float mean = wsum(x0 + x1) * (1.f / D);
  float d0 = x0 - mean, d1 = x1 - mean;
  float var = wsum(d0 * d0 + d1 * d1) * (1.f / D);
  float inv = rsqrtf(var + 1e-5f);
  float o0 = d0 * inv * g[lane] + be[lane];
  float o1 = d1 * inv * g[lane + 64] + be[lane + 64];
  int n = t >> 7, p = t & 127;
  size_t obase = (((size_t)b * N + n) * D) * P + p;
  out[obase + (size_t)lane * P] = o0;
  out[obase + (size_t)(lane + 64) * P] = o1;
}

extern "C" void kernel_launch(void* const* d_in, const int* in_sizes, int n_in,
                              void* d_out, int out_size, void* d_ws, size_t ws_size,
                              hipStream_t stream)
{
  (void)in_sizes; (void)n_in; (void)out_size; (void)ws_size;
  const float* x       = (const float*)d_in[0];
  const float* view    = (const float*)d_in[1];
  const float* wp_w    = (const float*)d_in[2];
  const float* wp_b    = (const float*)d_in[3];
  const float* m_in_w  = (const float*)d_in[4];
  const float* m_conv_w= (const float*)d_in[5];
  const float* m_conv_b= (const float*)d_in[6];
  const float* m_xproj = (const float*)d_in[7];
  const float* m_dt_w  = (const float*)d_in[8];
  const float* m_dt_b  = (const float*)d_in[9];
  const float* m_Alog  = (const float*)d_in[10];
  const float* m_Dp    = (const float*)d_in[11];
  const float* m_out_w = (const float*)d_in[12];
  const float* ffn_w1  = (const float*)d_in[13];
  const float* ffn_b1  = (const float*)d_in[14];
  const float* ffn_w2  = (const float*)d_in[15];
  const float* ffn_b2  = (const float*)d_in[16];
  const float* ln1_g   = (const float*)d_in[17];
  const float* ln1_b   = (const float*)d_in[18];
  const float* ln2_g   = (const float*)d_in[19];
  const float* ln2_b   = (const float*)d_in[20];
  const float* lnf_g   = (const float*)d_in[21];
  const float* lnf_b   = (const float*)d_in[22];
  float* out = (float*)d_out;

  float* W = (float*)d_ws;
  size_t off = 0;
  auto alloc = [&](size_t nfl) { float* p = W + off; off += (nfl + 3) & ~(size_t)3; return p; };
  float* U    = alloc((size_t)BL * D);
  float* XCC  = alloc((size_t)2 * BL * D);
  float* Zb   = alloc((size_t)2 * BL * D);   // first BL*D/2 also hosts XRbf post-scan
  float* DTb  = alloc((size_t)2 * BL * D);   // first BL*D also hosts XR post-scan
  float* BCb  = alloc((size_t)2 * BL * 2 * DS);
  float* HC   = alloc((size_t)2 * B * NC * D * DS);
  float* DTS  = alloc((size_t)2 * B * NC * D);
  float* HIN  = alloc((size_t)2 * B * NC * D * DS);  // also hosts XCCbf pre-scanB
  float* Ubf_f  = alloc((size_t)BL * D / 2);
  float* Hbf_f  = alloc((size_t)BL * 256 / 2);
  float* YM_f   = alloc((size_t)BL * 256 / 2);
  float* weff_f = alloc(262144 / 2);
  float* xpw_f  = alloc(20480 / 2);
  float* outw_f = alloc(65536 / 2);
  float* w1_f   = alloc(65536 / 2);
  float* w2_f   = alloc(65536 / 2);

  __bf16* Ubf    = (__bf16*)Ubf_f;
  __bf16* Hbf    = (__bf16*)Hbf_f;
  __bf16* YMbf   = (__bf16*)YM_f;
  __bf16* weff   = (__bf16*)weff_f;
  __bf16* xpw_bf = (__bf16*)xpw_f;
  __bf16* outw_bf= (__bf16*)outw_f;
  __bf16* w1_bf  = (__bf16*)w1_f;
  __bf16* w2_bf  = (__bf16*)w2_f;
  __bf16* XCCbf  = (__bf16*)HIN;   // dead before scanB writes HIN
  float*  XR     = DTb;            // DTb dead after scanC
  __bf16* XRbf   = (__bf16*)Zb;    // Zb dead after scanC

  k_prep<<<1872, 256, 0, stream>>>(m_in_w, m_conv_w, m_xproj, m_out_w, ffn_w1, ffn_w2,
                                   weff, xpw_bf, outw_bf, w1_bf, w2_bf);
  k_embed<<<(BL * D + 255) / 256, 256, 0, stream>>>(x, view, wp_w, wp_b, U, Ubf);

  for (int l = 0; l < EL; ++l) {
    const float* conv_b_l = m_conv_b + (size_t)l * 2 * D;
    const float* dt_w_l   = m_dt_w   + (size_t)l * 2 * D * DTR;
    const float* dt_b_l   = m_dt_b   + (size_t)l * 2 * D;
    const float* Alog_l   = m_Alog   + (size_t)l * 2 * D * DS;
    const float* Dp_l     = m_Dp     + (size_t)l * 2 * D;

    k_xzc      <<<dim3(2 * MT128, 4), 256, 0, stream>>>(Ubf, weff + (size_t)l * 2 * 256 * 256,
                                                        conv_b_l, XCC, XCCbf, Zb);
    k_xproj_dt <<<2 * MT128, 256, 0, stream>>>(XCCbf, xpw_bf + (size_t)l * 2 * 40 * 128,
                                               dt_w_l, dt_b_l, BCb, DTb);
    k_scanA    <<<2 * B * NC, 128, 0, stream>>>(DTb, XCC, BCb, Alog_l, HC, DTS);
    k_scanB    <<<2 * B, 128, 0, stream>>>(HC, DTS, Alog_l, HIN);
    k_scanC    <<<2 * B * NC, 128, 0, stream>>>(DTb, XCC, BCb, Zb, HIN, Alog_l, Dp_l, YMbf);
    k_outln    <<<MT64, 256, 0, stream>>>(YMbf, outw_bf + (size_t)l * 128 * 256, U,
                                          ln1_g + l * D, ln1_b + l * D, XR, XRbf);
    k_ffn1_mfma<<<dim3(MT128, 4), 256, 0, stream>>>(XRbf, w1_bf + (size_t)l * 256 * 128,
                                                    ffn_b1 + l * DFF, Hbf);
    k_ffn2_mfma<<<MT64, 256, 0, stream>>>(Hbf, w2_bf + (size_t)l * 128 * 256, ffn_b2 + l * D,
                                          XR, ln2_g + l * D, ln2_b + l * D, U, Ubf);
  }
  k_lnf_out<<<(B * N * P) / 4, 256, 0, stream>>>(U, lnf_g, lnf_b, out);
}